// Round 14
// baseline (576.814 us; speedup 1.0000x reference)
//
#include <hip/hip_runtime.h>
#include <stdint.h>

typedef __attribute__((ext_vector_type(8))) short short8;
typedef __attribute__((ext_vector_type(4))) float f32x4;
typedef __attribute__((ext_vector_type(4))) unsigned short us4;

#define MFMA16(a,b,c) __builtin_amdgcn_mfma_f32_16x16x32_bf16((a),(b),(c),0,0,0)

static __device__ __forceinline__ float bf2f(unsigned short u){
  union { float f; unsigned int i; } c; c.i = ((unsigned int)u) << 16; return c.f;
}
static __device__ __forceinline__ unsigned short f2bf(float f){
  union { float f; unsigned int i; } c; c.f = f;
  unsigned int x = c.i;
  unsigned int r = x + 0x7fffu + ((x >> 16) & 1u);
  return (unsigned short)(r >> 16);
}
static __device__ __forceinline__ short8 pack8(const float* v){
  short8 r;
  #pragma unroll
  for (int i = 0; i < 8; ++i) r[i] = (short)f2bf(v[i]);
  return r;
}

typedef const __attribute__((address_space(1))) void cg_void;
typedef __attribute__((address_space(3))) void lds_void;
static __device__ __forceinline__ void gl_lds16(const void* g, void* l){
  __builtin_amdgcn_global_load_lds((cg_void*)g, (lds_void*)l, 16, 0, 0);
}
// Non-temporal (SLC) A-stream variant: A bytes are consumed once from LDS,
// so don't let them allocate in L2/L3 and evict the hot B panel.
static __device__ __forceinline__ void gl_lds16_nt(const void* g, void* l){
  __builtin_amdgcn_global_load_lds((cg_void*)g, (lds_void*)l, 16, 0, 2);
}

#define MROWS 10240LL
#define LDA   10048
// g16 tiled layout: g16t[mtile][kt][16384 shorts]; chunk ch holds global
// (row = mtile*256 + (ch>>3), colblock = (ch&7)^(row&7)) of K-tile kt.
#define GTILE 16384LL

// XCD-aware remap for 240-block split-K grids.
static __device__ __forceinline__ void remap240(int bid, int& x, int& s){
  int v = (bid & 7) * 30 + (bid >> 3);
  s = v / 40;
  x = v % 40;
}

// ---- zero-pad Tbuf cols 10000..10047 for rows 0..511 ----
__global__ void k_zero(unsigned short* __restrict__ Tbuf){
  short8 z = {0,0,0,0,0,0,0,0};
  for (int c = blockIdx.x*256 + threadIdx.x; c < 512*6; c += gridDim.x*256){
    int row = c/6, k = c%6;
    *(short8*)(Tbuf + (long long)row*LDA + 10000 + k*8) = z;
  }
}

// ---- convert the 3 weight matrices in one launch ----
__global__ void k_conv_w(const float* __restrict__ a, unsigned short* __restrict__ oa, int na4,
                         const float* __restrict__ b, unsigned short* __restrict__ ob, int nb4,
                         const float* __restrict__ c, unsigned short* __restrict__ oc, int nc4){
  for (int i = blockIdx.x*blockDim.x + threadIdx.x; i < na4 + nb4 + nc4;
       i += gridDim.x*blockDim.x){
    const float* src; unsigned short* dst; int j = i;
    if (j < na4){ src = a; dst = oa; }
    else if (j < na4 + nb4){ j -= na4; src = b; dst = ob; }
    else { j -= na4 + nb4; src = c; dst = oc; }
    float4 f = *(const float4*)(src + (long long)j*4);
    us4 v; v.x=f2bf(f.x); v.y=f2bf(f.y); v.z=f2bf(f.z); v.w=f2bf(f.w);
    *(us4*)(dst + (long long)j*4) = v;
  }
}

// ---- transpose-convert z: f32 [10000][128] -> bf16 [128][10048] ----
__global__ void k_tconv_z(const float* __restrict__ z, unsigned short* __restrict__ o){
  __shared__ unsigned short t[64][65];
  const int rb = blockIdx.x*64, cb = blockIdx.y*64;
  #pragma unroll
  for (int it = 0; it < 4; ++it){
    int idx = it*256 + threadIdx.x;
    int r = idx >> 4, c4 = (idx & 15) * 4;
    float4 f = {0.f,0.f,0.f,0.f};
    if (rb + r < 10000) f = *(const float4*)(z + (long long)(rb+r)*128 + cb + c4);
    t[c4+0][r] = f2bf(f.x); t[c4+1][r] = f2bf(f.y);
    t[c4+2][r] = f2bf(f.z); t[c4+3][r] = f2bf(f.w);
  }
  __syncthreads();
  #pragma unroll
  for (int it = 0; it < 4; ++it){
    int idx = it*256 + threadIdx.x;
    int ro = idx >> 4, co4 = (idx & 15) * 4;
    us4 v; v.x=t[ro][co4]; v.y=t[ro][co4+1]; v.z=t[ro][co4+2]; v.w=t[ro][co4+3];
    *(us4*)(o + (long long)(cb+ro)*LDA + rb + co4) = v;
  }
}

// ======= fused t0: BM=256, BN=128, 8 waves (4M x 2N, wave 64x64) =======
// Reads f32 g (reg-staged, converts), writes g16 in TILED staging order +
// bf16 t0 partials. B (zT) via gl_lds. Grid 240 1D with XCD remap.
__global__ __launch_bounds__(512)
void k_gemm_t0(const float* __restrict__ g, const unsigned short* __restrict__ zT,
               unsigned short* __restrict__ g16, unsigned short* __restrict__ P, int S)
{
  constexpr int ldp = 128;
  __shared__ unsigned short sm[2][24576];   // A 16384 + B 8192 shorts

  const int tid = threadIdx.x;
  const int wid = tid >> 6, l = tid & 63;
  const int wm = wid >> 1, wn = wid & 1;
  const int lr = l & 15, lk = l >> 4;
  int mtile, s;
  remap240(blockIdx.x, mtile, s);
  const int mBase = mtile * 256;
  const int kt0 = (157*s)/S, kt1 = (157*(s+1))/S;

  int arow[4], acol8[4];
  #pragma unroll
  for (int i = 0; i < 4; ++i){
    int ch = tid + 512*i;
    int row = ch >> 3, gr = ch & 7;
    arow[i] = row; acol8[i] = ((gr ^ (row & 7)) * 8);
  }
  float fA[4][8];
  auto loadA = [&](int kt){
    #pragma unroll
    for (int i = 0; i < 4; ++i){
      int grow = mBase + arow[i];
      int col = kt*64 + acol8[i];
      if (grow < 10000 && col < 10000){
        float4 x = *(const float4*)(g + (long long)grow*10000 + col);
        float4 y = *(const float4*)(g + (long long)grow*10000 + col + 4);
        fA[i][0]=x.x; fA[i][1]=x.y; fA[i][2]=x.z; fA[i][3]=x.w;
        fA[i][4]=y.x; fA[i][5]=y.y; fA[i][6]=y.z; fA[i][7]=y.w;
      } else {
        #pragma unroll
        for (int j = 0; j < 8; ++j) fA[i][j] = 0.f;
      }
    }
  };
  auto writeA = [&](int buf, int kt){
    unsigned short* gt = g16 + ((long long)mtile*157 + kt)*GTILE;
    #pragma unroll
    for (int i = 0; i < 4; ++i){
      int ch = tid + 512*i;
      short8 v = pack8(fA[i]);
      *(short8*)(&sm[buf][ch*8]) = v;
      *(short8*)(gt + ch*8) = v;               // tiled staging-order write
    }
  };
  auto stageB = [&](int buf, int kt){
    unsigned short* dst = &sm[buf][16384];
    const unsigned short* Bk = zT + (long long)kt*64;
    #pragma unroll
    for (int i = 0; i < 2; ++i){
      int c = i*512 + tid; int row = c >> 3, gr = c & 7;
      gl_lds16(Bk + (long long)row*LDA + ((gr ^ (row & 7))*8), dst + c*8);
    }
  };

  f32x4 acc[4][4];
  #pragma unroll
  for (int i = 0; i < 4; ++i)
    #pragma unroll
    for (int j = 0; j < 4; ++j){ f32x4 zz = {0.f,0.f,0.f,0.f}; acc[i][j] = zz; }

  loadA(kt0); stageB(0, kt0); writeA(0, kt0);
  int cur = 0;
  for (int kt = kt0; kt < kt1; ++kt){
    __syncthreads();
    const bool pf = (kt + 1 < kt1);
    if (pf){ loadA(kt+1); stageB(cur^1, kt+1); }
    const unsigned short* sp = &sm[cur][0];
    #pragma unroll
    for (int ks = 0; ks < 2; ++ks){
      short8 a[4];
      #pragma unroll
      for (int i = 0; i < 4; ++i){
        int row = wm*64 + i*16 + lr;
        a[i] = *(const short8*)(sp + row*64 + (((4*ks+lk) ^ (row & 7))*8));
      }
      #pragma unroll
      for (int j = 0; j < 4; ++j){
        int rb = wn*64 + j*16 + lr;
        short8 b = *(const short8*)(sp + 16384 + rb*64 + (((4*ks+lk) ^ (rb & 7))*8));
        #pragma unroll
        for (int i = 0; i < 4; ++i)
          acc[i][j] = MFMA16(a[i], b, acc[i][j]);
      }
    }
    if (pf) writeA(cur^1, kt+1);
    cur ^= 1;
  }

  unsigned short* Pp = P + (long long)s*MROWS*ldp;
  #pragma unroll
  for (int i = 0; i < 4; ++i){
    const int row0 = mBase + wm*64 + i*16 + lk*4;
    #pragma unroll
    for (int j = 0; j < 4; ++j){
      const int col = wn*64 + j*16 + lr;
      #pragma unroll
      for (int r = 0; r < 4; ++r)
        Pp[(long long)(row0+r)*ldp + col] = f2bf(acc[i][j][r]);
    }
  }
}

// ======= 256xBN GEMM, split-K, bf16 partials =======
// A: TILED g16 via NT gl_lds (stream, no cache allocation -> B stays hot).
// B: reg-staged through the CACHED path (global_load -> VGPR -> ds_write).
template<int BN>
__global__ __launch_bounds__(512)
void k_gemm8(const unsigned short* __restrict__ A,
             const unsigned short* __restrict__ B,
             unsigned short* __restrict__ P, int S, int ldp)
{
  constexpr int WNS = BN/4;
  constexpr int NJ  = WNS/16;
  constexpr int BCH = BN/64;
  __shared__ unsigned short sm[2][16384 + BN*64];

  const int tid = threadIdx.x;
  const int wid = tid >> 6, l = tid & 63;
  const int wm = wid >> 2, wn = wid & 3;
  const int lr = l & 15, lk = l >> 4;
  int mtile, s;
  remap240(blockIdx.x, mtile, s);
  const int mBase = mtile * 256;
  const int kt0 = (157*s)/S, kt1 = (157*(s+1))/S;

  // A: linear tiled stream (contiguous 32 KB per K-tile per block), NT
  const unsigned short* Abase = A + (long long)mtile*157*GTILE + tid*8;
  auto stageA = [&](unsigned short* dst, int kt){
    const unsigned short* Ak = Abase + (long long)kt*GTILE;
    #pragma unroll
    for (int i = 0; i < 4; ++i)
      gl_lds16_nt(Ak + i*4096, dst + tid*8 + i*4096);
  };

  // B: cached loads to regs, ds_write later (same swizzled content layout)
  const unsigned short* gsrcB[BCH];
  int ldstB[BCH];
  #pragma unroll
  for (int i = 0; i < BCH; ++i){
    int ch = tid + 512*i;
    int row = ch >> 3, gc = (ch & 7) ^ (row & 7);
    gsrcB[i] = B + (long long)row*LDA + gc*8;
    ldstB[i] = 16384 + ch*8;
  }
  short8 breg[BCH];
  auto loadB = [&](int kt){
    const long long ko = (long long)kt*64;
    #pragma unroll
    for (int i = 0; i < BCH; ++i)
      breg[i] = *(const short8*)(gsrcB[i] + ko);
  };
  auto writeB = [&](unsigned short* dst){
    #pragma unroll
    for (int i = 0; i < BCH; ++i)
      *(short8*)(dst + ldstB[i]) = breg[i];
  };

  f32x4 acc[8][NJ];
  #pragma unroll
  for (int i = 0; i < 8; ++i)
    #pragma unroll
    for (int j = 0; j < NJ; ++j){ f32x4 zz = {0.f,0.f,0.f,0.f}; acc[i][j] = zz; }

  // prologue: full kt0 into buffer 0
  stageA(&sm[0][0], kt0);
  loadB(kt0);
  writeB(&sm[0][0]);

  int cur = 0;
  for (int kt = kt0; kt < kt1; ++kt){
    __syncthreads();                  // kt fully in sm[cur] (drains vm+lgkm)
    const bool pf = (kt + 1 < kt1);
    if (pf){
      stageA(&sm[cur^1][0], kt+1);    // A prefetch (NT stream)
      loadB(kt+1);                    // B prefetch (cached, to regs)
    }

    const unsigned short* sp = &sm[cur][0];
    short8 bfr[NJ][2];
    #pragma unroll
    for (int jj = 0; jj < NJ; ++jj){
      const int row = wn*WNS + jj*16 + lr;
      #pragma unroll
      for (int ks = 0; ks < 2; ++ks)
        bfr[jj][ks] = *(const short8*)(sp + 16384 + row*64 + (((ks*4+lk) ^ (row & 7))*8));
    }
    #pragma unroll
    for (int ih = 0; ih < 2; ++ih){
      short8 af[4][2];
      #pragma unroll
      for (int ii = 0; ii < 4; ++ii){
        const int row = wm*128 + ih*64 + ii*16 + lr;
        #pragma unroll
        for (int ks = 0; ks < 2; ++ks)
          af[ii][ks] = *(const short8*)(sp + row*64 + (((ks*4+lk) ^ (row & 7))*8));
      }
      __builtin_amdgcn_s_setprio(1);
      #pragma unroll
      for (int ks = 0; ks < 2; ++ks)
        #pragma unroll
        for (int ii = 0; ii < 4; ++ii)
          #pragma unroll
          for (int jj = 0; jj < NJ; ++jj)
            acc[ih*4+ii][jj] = MFMA16(af[ii][ks], bfr[jj][ks], acc[ih*4+ii][jj]);
      __builtin_amdgcn_s_setprio(0);
    }
    // land B(kt+1) into the next buffer (compiler inserts the vmcnt wait
    // for breg HERE, after the MFMA block — A prefetch latency stays hidden)
    if (pf) writeB(&sm[cur^1][0]);
    cur ^= 1;
  }

  unsigned short* Pp = P + (long long)s*MROWS*ldp;
  #pragma unroll
  for (int i = 0; i < 8; ++i){
    const int row0 = mBase + wm*128 + i*16 + lk*4;
    #pragma unroll
    for (int j = 0; j < NJ; ++j){
      const int col = wn*WNS + j*16 + lr;
      #pragma unroll
      for (int r = 0; r < 4; ++r)
        Pp[(long long)(row0+r)*ldp + col] = f2bf(acc[i][j][r]);
    }
  }
}

// ---- fused small GEMM over summed bf16 partials ----
// MODE 0: (optional relu) -> o1 = outT bf16 [NW][10048]
// MODE 1: relu -> o3 = z_ row [10000][256]; rownorm -> o1 = znT, o2 = zn row
template<int NW, int KW, int LDP, int S, int MODE>
__global__ __launch_bounds__(320)
void k_small(const unsigned short* __restrict__ P,
             const unsigned short* __restrict__ W,
             unsigned short* __restrict__ o1,
             unsigned short* __restrict__ o2,
             unsigned short* __restrict__ o3,
             int doRelu)
{
  const int tid = threadIdx.x, w = tid >> 6, l = tid & 63;
  const int lr = l & 15, lk = l >> 4;
  const int mBase = blockIdx.x * 80;
  constexpr int NF = NW/16;
  constexpr long long SSTR = MROWS*(long long)LDP;

  f32x4 acc[NF];
  #pragma unroll
  for (int f = 0; f < NF; ++f){ f32x4 zz = {0.f,0.f,0.f,0.f}; acc[f] = zz; }

  const unsigned short* ap = P + (long long)(mBase + 16*w + lr)*LDP + lk*8;
  #pragma unroll
  for (int kc = 0; kc < KW/32; ++kc){
    float av[8];
    short8 v0 = *(const short8*)(ap + kc*32);
    #pragma unroll
    for (int e = 0; e < 8; ++e) av[e] = bf2f((unsigned short)v0[e]);
    #pragma unroll
    for (int s2 = 1; s2 < S; ++s2){
      short8 v = *(const short8*)(ap + (long long)s2*SSTR + kc*32);
      #pragma unroll
      for (int e = 0; e < 8; ++e) av[e] += bf2f((unsigned short)v[e]);
    }
    short8 a = pack8(av);
    #pragma unroll
    for (int f = 0; f < NF; ++f){
      short8 b = *(const short8*)(W + (long long)(16*f+lr)*KW + kc*32 + lk*8);
      acc[f] = MFMA16(a, b, acc[f]);
    }
  }

  const int row0 = mBase + 16*w + lk*4;
  if constexpr (MODE == 0){
    #pragma unroll
    for (int f = 0; f < NF; ++f){
      us4 v;
      #pragma unroll
      for (int r = 0; r < 4; ++r){
        float x = acc[f][r];
        if (doRelu) x = fmaxf(x, 0.0f);
        v[r] = f2bf(x);
      }
      *(us4*)(o1 + (long long)(16*f+lr)*LDA + row0) = v;
    }
  } else {
    float ss[4] = {0.f,0.f,0.f,0.f};
    #pragma unroll
    for (int f = 0; f < NF; ++f)
      #pragma unroll
      for (int r = 0; r < 4; ++r){
        float v = fmaxf(acc[f][r], 0.0f);
        acc[f][r] = v;
        ss[r] += v*v;
      }
    #pragma unroll
    for (int r = 0; r < 4; ++r){
      #pragma unroll
      for (int off = 1; off <= 8; off <<= 1)
        ss[r] += __shfl_xor(ss[r], off, 64);
      ss[r] = 1.0f / fmaxf(sqrtf(ss[r]), 1e-12f);
    }
    #pragma unroll
    for (int f = 0; f < NF; ++f){
      const int col = 16*f + lr;
      us4 vn;
      #pragma unroll
      for (int r = 0; r < 4; ++r){
        float zr = acc[f][r];
        float nr = zr * ss[r];
        vn[r] = f2bf(nr);
        o2[(long long)(row0+r)*256 + col] = vn[r];     // zn row-major
        o3[(long long)(row0+r)*256 + col] = f2bf(zr);  // z_ row-major
      }
      *(us4*)(o1 + (long long)col*LDA + row0) = vn;    // znT
    }
  }
}

// ---- fused reduce(bf16 partials) + APPNP epilogue + TRANSPOSED write ----
__global__ void k_reduce_T(const unsigned short* __restrict__ P, int S, int ldp, int colOff,
                           unsigned short* __restrict__ outT,
                           const unsigned short* __restrict__ H)
{
  __shared__ unsigned short t[64][65];
  const int rb = blockIdx.x*64, cb = blockIdx.y*64;
  const long long stride = MROWS * (long long)ldp;
  #pragma unroll
  for (int it = 0; it < 4; ++it){
    int idx = it*256 + threadIdx.x;
    int r = idx >> 4, c4 = (idx & 15)*4;
    int row = rb + r;
    float sv[4] = {0.f,0.f,0.f,0.f};
    if (row < 10000){
      const unsigned short* p = P + (long long)row*ldp + colOff + cb + c4;
      for (int s2 = 0; s2 < S; ++s2){
        us4 tt = *(const us4*)(p + (long long)s2*stride);
        sv[0] += bf2f(tt.x); sv[1] += bf2f(tt.y);
        sv[2] += bf2f(tt.z); sv[3] += bf2f(tt.w);
      }
      us4 h = *(const us4*)(H + (long long)row*256 + cb + c4);
      sv[0] = 0.5f*sv[0] + 0.5f*bf2f(h.x);
      sv[1] = 0.5f*sv[1] + 0.5f*bf2f(h.y);
      sv[2] = 0.5f*sv[2] + 0.5f*bf2f(h.z);
      sv[3] = 0.5f*sv[3] + 0.5f*bf2f(h.w);
    }
    t[c4+0][r] = f2bf(sv[0]); t[c4+1][r] = f2bf(sv[1]);
    t[c4+2][r] = f2bf(sv[2]); t[c4+3][r] = f2bf(sv[3]);
  }
  __syncthreads();
  #pragma unroll
  for (int it = 0; it < 4; ++it){
    int idx = it*256 + threadIdx.x;
    int ro = idx >> 4, co4 = (idx & 15)*4;
    us4 v; v.x=t[ro][co4]; v.y=t[ro][co4+1]; v.z=t[ro][co4+2]; v.w=t[ro][co4+3];
    *(us4*)(outT + (long long)(cb+ro)*LDA + rb + co4) = v;
  }
}

// ---- reduce partials + sigmoid -> f32 res [10000][128] ----
__global__ void k_reduce_sig(const unsigned short* __restrict__ P, int S,
                             float* __restrict__ out)
{
  const long long stride = MROWS * 128LL;
  const int idx = blockIdx.x*256 + threadIdx.x;
  const int row = idx >> 5;
  const int c4 = (idx & 31)*4;
  const unsigned short* p = P + (long long)row*128 + c4;
  float sv[4] = {0.f,0.f,0.f,0.f};
  for (int s2 = 0; s2 < S; ++s2){
    us4 tt = *(const us4*)(p + (long long)s2*stride);
    sv[0] += bf2f(tt.x); sv[1] += bf2f(tt.y);
    sv[2] += bf2f(tt.z); sv[3] += bf2f(tt.w);
  }
  float4 o;
  o.x = 1.0f/(1.0f + expf(-sv[0]));
  o.y = 1.0f/(1.0f + expf(-sv[1]));
  o.z = 1.0f/(1.0f + expf(-sv[2]));
  o.w = 1.0f/(1.0f + expf(-sv[3]));
  *(float4*)(out + (long long)row*128 + c4) = o;
}

// ---- final reduce: Z3 = 0.5*sum + 0.5*zn -> f32 out ----
__global__ void k_reduce2(const unsigned short* __restrict__ P, int S, int ldp,
                          float* __restrict__ out, const unsigned short* __restrict__ H)
{
  const long long stride = MROWS * (long long)ldp;
  const int idx = blockIdx.x*256 + threadIdx.x;
  const int row = idx >> 6;
  const int c4 = (idx & 63)*4;
  const unsigned short* p = P + (long long)row*ldp + c4;
  float sv[4] = {0.f,0.f,0.f,0.f};
  for (int s2 = 0; s2 < S; ++s2){
    us4 tt = *(const us4*)(p + (long long)s2*stride);
    sv[0] += bf2f(tt.x); sv[1] += bf2f(tt.y);
    sv[2] += bf2f(tt.z); sv[3] += bf2f(tt.w);
  }
  us4 h = *(const us4*)(H + (long long)row*256 + c4);
  float4 o;
  o.x = 0.5f*sv[0] + 0.5f*bf2f(h.x);
  o.y = 0.5f*sv[1] + 0.5f*bf2f(h.y);
  o.z = 0.5f*sv[2] + 0.5f*bf2f(h.z);
  o.w = 0.5f*sv[3] + 0.5f*bf2f(h.w);
  *(float4*)(out + (long long)row*256 + c4) = o;
}

extern "C" void kernel_launch(void* const* d_in, const int* in_sizes, int n_in,
                              void* d_out, int out_size, void* d_ws, size_t ws_size,
                              hipStream_t stream)
{
  const float* g   = (const float*)d_in[0];
  const float* z   = (const float*)d_in[1];
  const float* W1  = (const float*)d_in[2];
  const float* W1_ = (const float*)d_in[3];
  const float* W2  = (const float*)d_in[4];

  char* ws = (char*)d_ws;
  size_t off = 0;
  auto alloc = [&](size_t bytes)->void*{
    void* p = ws + off; off += (bytes + 255) & ~(size_t)255; return p;
  };
  unsigned short* g16  = (unsigned short*)alloc(40ULL*157*GTILE*2);  // tiled, 206 MB
  unsigned short* zT   = (unsigned short*)alloc(128ULL*10048*2);
  unsigned short* W1c  = (unsigned short*)alloc(256ULL*128*2);
  unsigned short* W1_c = (unsigned short*)alloc(256ULL*256*2);
  unsigned short* W2c  = (unsigned short*)alloc(128ULL*256*2);
  unsigned short* Tbuf = (unsigned short*)alloc(512ULL*10048*2);
  unsigned short* zn   = (unsigned short*)alloc(10000ULL*256*2);
  unsigned short* Xbuf = (unsigned short*)alloc(10000ULL*256*2);
  unsigned short* P    = (unsigned short*)alloc(10240ULL*1536*2);
  (void)ws_size; (void)in_sizes; (void)n_in; (void)out_size;

  float* res  = (float*)d_out;
  float* Zout = (float*)d_out + 10000LL*128;
  unsigned short* y2T = Tbuf + 256LL*LDA;

  k_zero<<<dim3(12), dim3(256), 0, stream>>>(Tbuf);
  k_tconv_z<<<dim3(157,2), dim3(256), 0, stream>>>(z, zT);
  k_conv_w<<<dim3(120), dim3(256), 0, stream>>>(W1, W1c, 256*128/4,
                                                W1_, W1_c, 256*256/4,
                                                W2, W2c, 128*256/4);

  // t0 = g @ z (writes tiled g16 + partials), S=6, XCD-remapped 240 blocks
  k_gemm_t0<<<dim3(240), dim3(512), 0, stream>>>(g, zT, g16, P, 6);
  // z1^T -> Tbuf rows 0..255
  k_small<256,128,128,6,0><<<dim3(125), dim3(320), 0, stream>>>(P, W1c, Tbuf, nullptr, nullptr, 1);
  // t1 = g @ z1
  k_gemm8<256><<<dim3(240), dim3(512), 0, stream>>>(g16, Tbuf, P, 6, 256);
  // znT -> Tbuf rows 0..255, zn row, z_ row -> Xbuf
  k_small<256,256,256,6,1><<<dim3(125), dim3(320), 0, stream>>>(P, W1_c, Tbuf, zn, Xbuf, 0);
  // y2^T = T(z_ @ W2^T) -> Tbuf rows 256..383
  k_small<128,256,256,1,0><<<dim3(125), dim3(320), 0, stream>>>(Xbuf, W2c, y2T, nullptr, nullptr, 0);
  // u1 = g @ zn
  k_gemm8<256><<<dim3(240), dim3(512), 0, stream>>>(g16, Tbuf, P, 6, 256);
  // Z1^T -> Tbuf rows 0..255
  k_reduce_T<<<dim3(157,4), dim3(256), 0, stream>>>(P, 6, 256, 0, Tbuf, zn);
  // r = g @ y2 (N=128)
  k_gemm8<128><<<dim3(240), dim3(512), 0, stream>>>(g16, y2T, P, 6, 128);
  // res = sigmoid(r)
  k_reduce_sig<<<dim3(1250), dim3(256), 0, stream>>>(P, 6, res);
  // Z2
  k_gemm8<256><<<dim3(240), dim3(512), 0, stream>>>(g16, Tbuf, P, 6, 256);
  k_reduce_T<<<dim3(157,4), dim3(256), 0, stream>>>(P, 6, 256, 0, Tbuf, zn);
  // Z3 -> f32 d_out
  k_gemm8<256><<<dim3(240), dim3(512), 0, stream>>>(g16, Tbuf, P, 6, 256);
  k_reduce2<<<dim3(2500), dim3(256), 0, stream>>>(P, 6, 256, Zout, zn);
}

// Round 15
// 518.588 us; speedup vs baseline: 1.1123x; 1.1123x over previous
//
#include <hip/hip_runtime.h>
#include <stdint.h>

typedef __attribute__((ext_vector_type(8))) short short8;
typedef __attribute__((ext_vector_type(4))) float f32x4;
typedef __attribute__((ext_vector_type(4))) unsigned short us4;

#define MFMA16(a,b,c) __builtin_amdgcn_mfma_f32_16x16x32_bf16((a),(b),(c),0,0,0)

static __device__ __forceinline__ float bf2f(unsigned short u){
  union { float f; unsigned int i; } c; c.i = ((unsigned int)u) << 16; return c.f;
}
static __device__ __forceinline__ unsigned short f2bf(float f){
  union { float f; unsigned int i; } c; c.f = f;
  unsigned int x = c.i;
  unsigned int r = x + 0x7fffu + ((x >> 16) & 1u);
  return (unsigned short)(r >> 16);
}
static __device__ __forceinline__ short8 pack8(const float* v){
  short8 r;
  #pragma unroll
  for (int i = 0; i < 8; ++i) r[i] = (short)f2bf(v[i]);
  return r;
}

typedef const __attribute__((address_space(1))) void cg_void;
typedef __attribute__((address_space(3))) void lds_void;
static __device__ __forceinline__ void gl_lds16(const void* g, void* l){
  __builtin_amdgcn_global_load_lds((cg_void*)g, (lds_void*)l, 16, 0, 0);
}

#define MROWS 10240LL
#define LDA   10048
// g16 tiled layout: g16t[mtile][kt][16384 shorts]; chunk ch holds global
// (row = mtile*256 + (ch>>3), colblock = (ch&7)^(row&7)) of K-tile kt.
#define GTILE 16384LL

// XCD-aware remap for 240-block split-K grids.
static __device__ __forceinline__ void remap240(int bid, int& x, int& s){
  int v = (bid & 7) * 30 + (bid >> 3);
  s = v / 40;
  x = v % 40;
}

// ---- zero-pad Tbuf cols 10000..10047 for rows 0..511 ----
__global__ void k_zero(unsigned short* __restrict__ Tbuf){
  short8 z = {0,0,0,0,0,0,0,0};
  for (int c = blockIdx.x*256 + threadIdx.x; c < 512*6; c += gridDim.x*256){
    int row = c/6, k = c%6;
    *(short8*)(Tbuf + (long long)row*LDA + 10000 + k*8) = z;
  }
}

// ---- convert the 3 weight matrices in one launch ----
__global__ void k_conv_w(const float* __restrict__ a, unsigned short* __restrict__ oa, int na4,
                         const float* __restrict__ b, unsigned short* __restrict__ ob, int nb4,
                         const float* __restrict__ c, unsigned short* __restrict__ oc, int nc4){
  for (int i = blockIdx.x*blockDim.x + threadIdx.x; i < na4 + nb4 + nc4;
       i += gridDim.x*blockDim.x){
    const float* src; unsigned short* dst; int j = i;
    if (j < na4){ src = a; dst = oa; }
    else if (j < na4 + nb4){ j -= na4; src = b; dst = ob; }
    else { j -= na4 + nb4; src = c; dst = oc; }
    float4 f = *(const float4*)(src + (long long)j*4);
    us4 v; v.x=f2bf(f.x); v.y=f2bf(f.y); v.z=f2bf(f.z); v.w=f2bf(f.w);
    *(us4*)(dst + (long long)j*4) = v;
  }
}

// ---- transpose-convert z: f32 [10000][128] -> bf16 [128][10048] ----
__global__ void k_tconv_z(const float* __restrict__ z, unsigned short* __restrict__ o){
  __shared__ unsigned short t[64][65];
  const int rb = blockIdx.x*64, cb = blockIdx.y*64;
  #pragma unroll
  for (int it = 0; it < 4; ++it){
    int idx = it*256 + threadIdx.x;
    int r = idx >> 4, c4 = (idx & 15) * 4;
    float4 f = {0.f,0.f,0.f,0.f};
    if (rb + r < 10000) f = *(const float4*)(z + (long long)(rb+r)*128 + cb + c4);
    t[c4+0][r] = f2bf(f.x); t[c4+1][r] = f2bf(f.y);
    t[c4+2][r] = f2bf(f.z); t[c4+3][r] = f2bf(f.w);
  }
  __syncthreads();
  #pragma unroll
  for (int it = 0; it < 4; ++it){
    int idx = it*256 + threadIdx.x;
    int ro = idx >> 4, co4 = (idx & 15) * 4;
    us4 v; v.x=t[ro][co4]; v.y=t[ro][co4+1]; v.z=t[ro][co4+2]; v.w=t[ro][co4+3];
    *(us4*)(o + (long long)(cb+ro)*LDA + rb + co4) = v;
  }
}

// ======= fused t0: BM=256, BN=128, 8 waves (4M x 2N, wave 64x64) =======
// Reads f32 g (reg-staged, converts), writes g16 in TILED staging order +
// bf16 t0 partials. B (zT) via gl_lds. Grid 240 1D with XCD remap.
__global__ __launch_bounds__(512)
void k_gemm_t0(const float* __restrict__ g, const unsigned short* __restrict__ zT,
               unsigned short* __restrict__ g16, unsigned short* __restrict__ P, int S)
{
  constexpr int ldp = 128;
  __shared__ unsigned short sm[2][24576];   // A 16384 + B 8192 shorts

  const int tid = threadIdx.x;
  const int wid = tid >> 6, l = tid & 63;
  const int wm = wid >> 1, wn = wid & 1;
  const int lr = l & 15, lk = l >> 4;
  int mtile, s;
  remap240(blockIdx.x, mtile, s);
  const int mBase = mtile * 256;
  const int kt0 = (157*s)/S, kt1 = (157*(s+1))/S;

  int arow[4], acol8[4];
  #pragma unroll
  for (int i = 0; i < 4; ++i){
    int ch = tid + 512*i;
    int row = ch >> 3, gr = ch & 7;
    arow[i] = row; acol8[i] = ((gr ^ (row & 7)) * 8);
  }
  float fA[4][8];
  auto loadA = [&](int kt){
    #pragma unroll
    for (int i = 0; i < 4; ++i){
      int grow = mBase + arow[i];
      int col = kt*64 + acol8[i];
      if (grow < 10000 && col < 10000){
        float4 x = *(const float4*)(g + (long long)grow*10000 + col);
        float4 y = *(const float4*)(g + (long long)grow*10000 + col + 4);
        fA[i][0]=x.x; fA[i][1]=x.y; fA[i][2]=x.z; fA[i][3]=x.w;
        fA[i][4]=y.x; fA[i][5]=y.y; fA[i][6]=y.z; fA[i][7]=y.w;
      } else {
        #pragma unroll
        for (int j = 0; j < 8; ++j) fA[i][j] = 0.f;
      }
    }
  };
  auto writeA = [&](int buf, int kt){
    unsigned short* gt = g16 + ((long long)mtile*157 + kt)*GTILE;
    #pragma unroll
    for (int i = 0; i < 4; ++i){
      int ch = tid + 512*i;
      short8 v = pack8(fA[i]);
      *(short8*)(&sm[buf][ch*8]) = v;
      *(short8*)(gt + ch*8) = v;               // tiled staging-order write
    }
  };
  auto stageB = [&](int buf, int kt){
    unsigned short* dst = &sm[buf][16384];
    const unsigned short* Bk = zT + (long long)kt*64;
    #pragma unroll
    for (int i = 0; i < 2; ++i){
      int c = i*512 + tid; int row = c >> 3, gr = c & 7;
      gl_lds16(Bk + (long long)row*LDA + ((gr ^ (row & 7))*8), dst + c*8);
    }
  };

  f32x4 acc[4][4];
  #pragma unroll
  for (int i = 0; i < 4; ++i)
    #pragma unroll
    for (int j = 0; j < 4; ++j){ f32x4 zz = {0.f,0.f,0.f,0.f}; acc[i][j] = zz; }

  loadA(kt0); stageB(0, kt0); writeA(0, kt0);
  int cur = 0;
  for (int kt = kt0; kt < kt1; ++kt){
    __syncthreads();
    const bool pf = (kt + 1 < kt1);
    if (pf){ loadA(kt+1); stageB(cur^1, kt+1); }
    const unsigned short* sp = &sm[cur][0];
    #pragma unroll
    for (int ks = 0; ks < 2; ++ks){
      short8 a[4];
      #pragma unroll
      for (int i = 0; i < 4; ++i){
        int row = wm*64 + i*16 + lr;
        a[i] = *(const short8*)(sp + row*64 + (((4*ks+lk) ^ (row & 7))*8));
      }
      #pragma unroll
      for (int j = 0; j < 4; ++j){
        int rb = wn*64 + j*16 + lr;
        short8 b = *(const short8*)(sp + 16384 + rb*64 + (((4*ks+lk) ^ (rb & 7))*8));
        #pragma unroll
        for (int i = 0; i < 4; ++i)
          acc[i][j] = MFMA16(a[i], b, acc[i][j]);
      }
    }
    if (pf) writeA(cur^1, kt+1);
    cur ^= 1;
  }

  unsigned short* Pp = P + (long long)s*MROWS*ldp;
  #pragma unroll
  for (int i = 0; i < 4; ++i){
    const int row0 = mBase + wm*64 + i*16 + lk*4;
    #pragma unroll
    for (int j = 0; j < 4; ++j){
      const int col = wn*64 + j*16 + lr;
      #pragma unroll
      for (int r = 0; r < 4; ++r)
        Pp[(long long)(row0+r)*ldp + col] = f2bf(acc[i][j][r]);
    }
  }
}

// ======= 256xBN GEMM, split-K, bf16 partials =======
// A: TILED g16 via gl_lds (HBM/L3 stream). B: reg-staged through the CACHED
// path (global_load -> VGPR -> ds_write).
template<int BN>
__global__ __launch_bounds__(512)
void k_gemm8(const unsigned short* __restrict__ A,
             const unsigned short* __restrict__ B,
             unsigned short* __restrict__ P, int S, int ldp)
{
  constexpr int WNS = BN/4;
  constexpr int NJ  = WNS/16;
  constexpr int BCH = BN/64;
  __shared__ unsigned short sm[2][16384 + BN*64];

  const int tid = threadIdx.x;
  const int wid = tid >> 6, l = tid & 63;
  const int wm = wid >> 2, wn = wid & 3;
  const int lr = l & 15, lk = l >> 4;
  int mtile, s;
  remap240(blockIdx.x, mtile, s);
  const int mBase = mtile * 256;
  const int kt0 = (157*s)/S, kt1 = (157*(s+1))/S;

  // A: linear tiled stream (contiguous 32 KB per K-tile per block)
  const unsigned short* Abase = A + (long long)mtile*157*GTILE + tid*8;
  auto stageA = [&](unsigned short* dst, int kt){
    const unsigned short* Ak = Abase + (long long)kt*GTILE;
    #pragma unroll
    for (int i = 0; i < 4; ++i)
      gl_lds16(Ak + i*4096, dst + tid*8 + i*4096);
  };

  // B: cached loads to regs, ds_write later (same swizzled content layout)
  const unsigned short* gsrcB[BCH];
  int ldstB[BCH];
  #pragma unroll
  for (int i = 0; i < BCH; ++i){
    int ch = tid + 512*i;
    int row = ch >> 3, gc = (ch & 7) ^ (row & 7);
    gsrcB[i] = B + (long long)row*LDA + gc*8;
    ldstB[i] = 16384 + ch*8;
  }
  short8 breg[BCH];
  auto loadB = [&](int kt){
    const long long ko = (long long)kt*64;
    #pragma unroll
    for (int i = 0; i < BCH; ++i)
      breg[i] = *(const short8*)(gsrcB[i] + ko);
  };
  auto writeB = [&](unsigned short* dst){
    #pragma unroll
    for (int i = 0; i < BCH; ++i)
      *(short8*)(dst + ldstB[i]) = breg[i];
  };

  f32x4 acc[8][NJ];
  #pragma unroll
  for (int i = 0; i < 8; ++i)
    #pragma unroll
    for (int j = 0; j < NJ; ++j){ f32x4 zz = {0.f,0.f,0.f,0.f}; acc[i][j] = zz; }

  // prologue: full kt0 into buffer 0
  stageA(&sm[0][0], kt0);
  loadB(kt0);
  writeB(&sm[0][0]);

  int cur = 0;
  for (int kt = kt0; kt < kt1; ++kt){
    __syncthreads();                  // kt fully in sm[cur] (drains vm+lgkm)
    const bool pf = (kt + 1 < kt1);
    if (pf){
      stageA(&sm[cur^1][0], kt+1);    // A prefetch (gl_lds stream)
      loadB(kt+1);                    // B prefetch (cached, to regs)
    }

    const unsigned short* sp = &sm[cur][0];
    short8 bfr[NJ][2];
    #pragma unroll
    for (int jj = 0; jj < NJ; ++jj){
      const int row = wn*WNS + jj*16 + lr;
      #pragma unroll
      for (int ks = 0; ks < 2; ++ks)
        bfr[jj][ks] = *(const short8*)(sp + 16384 + row*64 + (((ks*4+lk) ^ (row & 7))*8));
    }
    #pragma unroll
    for (int ih = 0; ih < 2; ++ih){
      short8 af[4][2];
      #pragma unroll
      for (int ii = 0; ii < 4; ++ii){
        const int row = wm*128 + ih*64 + ii*16 + lr;
        #pragma unroll
        for (int ks = 0; ks < 2; ++ks)
          af[ii][ks] = *(const short8*)(sp + row*64 + (((ks*4+lk) ^ (row & 7))*8));
      }
      __builtin_amdgcn_s_setprio(1);
      #pragma unroll
      for (int ks = 0; ks < 2; ++ks)
        #pragma unroll
        for (int ii = 0; ii < 4; ++ii)
          #pragma unroll
          for (int jj = 0; jj < NJ; ++jj)
            acc[ih*4+ii][jj] = MFMA16(af[ii][ks], bfr[jj][ks], acc[ih*4+ii][jj]);
      __builtin_amdgcn_s_setprio(0);
    }
    // land B(kt+1) into the next buffer (compiler inserts the vmcnt wait
    // for breg HERE, after the MFMA block — A prefetch latency stays hidden)
    if (pf) writeB(&sm[cur^1][0]);
    cur ^= 1;
  }

  unsigned short* Pp = P + (long long)s*MROWS*ldp;
  #pragma unroll
  for (int i = 0; i < 8; ++i){
    const int row0 = mBase + wm*128 + i*16 + lk*4;
    #pragma unroll
    for (int j = 0; j < NJ; ++j){
      const int col = wn*WNS + j*16 + lr;
      #pragma unroll
      for (int r = 0; r < 4; ++r)
        Pp[(long long)(row0+r)*ldp + col] = f2bf(acc[i][j][r]);
    }
  }
}

// ---- fused small GEMM over summed bf16 partials ----
// MODE 0: (optional relu) -> o1 = outT bf16 [NW][10048]
// MODE 1: relu -> o3 = z_ row [10000][256]; rownorm -> o1 = znT, o2 = zn row
template<int NW, int KW, int LDP, int S, int MODE>
__global__ __launch_bounds__(320)
void k_small(const unsigned short* __restrict__ P,
             const unsigned short* __restrict__ W,
             unsigned short* __restrict__ o1,
             unsigned short* __restrict__ o2,
             unsigned short* __restrict__ o3,
             int doRelu)
{
  const int tid = threadIdx.x, w = tid >> 6, l = tid & 63;
  const int lr = l & 15, lk = l >> 4;
  const int mBase = blockIdx.x * 80;
  constexpr int NF = NW/16;
  constexpr long long SSTR = MROWS*(long long)LDP;

  f32x4 acc[NF];
  #pragma unroll
  for (int f = 0; f < NF; ++f){ f32x4 zz = {0.f,0.f,0.f,0.f}; acc[f] = zz; }

  const unsigned short* ap = P + (long long)(mBase + 16*w + lr)*LDP + lk*8;
  #pragma unroll
  for (int kc = 0; kc < KW/32; ++kc){
    float av[8];
    short8 v0 = *(const short8*)(ap + kc*32);
    #pragma unroll
    for (int e = 0; e < 8; ++e) av[e] = bf2f((unsigned short)v0[e]);
    #pragma unroll
    for (int s2 = 1; s2 < S; ++s2){
      short8 v = *(const short8*)(ap + (long long)s2*SSTR + kc*32);
      #pragma unroll
      for (int e = 0; e < 8; ++e) av[e] += bf2f((unsigned short)v[e]);
    }
    short8 a = pack8(av);
    #pragma unroll
    for (int f = 0; f < NF; ++f){
      short8 b = *(const short8*)(W + (long long)(16*f+lr)*KW + kc*32 + lk*8);
      acc[f] = MFMA16(a, b, acc[f]);
    }
  }

  const int row0 = mBase + 16*w + lk*4;
  if constexpr (MODE == 0){
    #pragma unroll
    for (int f = 0; f < NF; ++f){
      us4 v;
      #pragma unroll
      for (int r = 0; r < 4; ++r){
        float x = acc[f][r];
        if (doRelu) x = fmaxf(x, 0.0f);
        v[r] = f2bf(x);
      }
      *(us4*)(o1 + (long long)(16*f+lr)*LDA + row0) = v;
    }
  } else {
    float ss[4] = {0.f,0.f,0.f,0.f};
    #pragma unroll
    for (int f = 0; f < NF; ++f)
      #pragma unroll
      for (int r = 0; r < 4; ++r){
        float v = fmaxf(acc[f][r], 0.0f);
        acc[f][r] = v;
        ss[r] += v*v;
      }
    #pragma unroll
    for (int r = 0; r < 4; ++r){
      #pragma unroll
      for (int off = 1; off <= 8; off <<= 1)
        ss[r] += __shfl_xor(ss[r], off, 64);
      ss[r] = 1.0f / fmaxf(sqrtf(ss[r]), 1e-12f);
    }
    #pragma unroll
    for (int f = 0; f < NF; ++f){
      const int col = 16*f + lr;
      us4 vn;
      #pragma unroll
      for (int r = 0; r < 4; ++r){
        float zr = acc[f][r];
        float nr = zr * ss[r];
        vn[r] = f2bf(nr);
        o2[(long long)(row0+r)*256 + col] = vn[r];     // zn row-major
        o3[(long long)(row0+r)*256 + col] = f2bf(zr);  // z_ row-major
      }
      *(us4*)(o1 + (long long)col*LDA + row0) = vn;    // znT
    }
  }
}

// ---- fused reduce(bf16 partials) + APPNP epilogue + TRANSPOSED write ----
__global__ void k_reduce_T(const unsigned short* __restrict__ P, int S, int ldp, int colOff,
                           unsigned short* __restrict__ outT,
                           const unsigned short* __restrict__ H)
{
  __shared__ unsigned short t[64][65];
  const int rb = blockIdx.x*64, cb = blockIdx.y*64;
  const long long stride = MROWS * (long long)ldp;
  #pragma unroll
  for (int it = 0; it < 4; ++it){
    int idx = it*256 + threadIdx.x;
    int r = idx >> 4, c4 = (idx & 15)*4;
    int row = rb + r;
    float sv[4] = {0.f,0.f,0.f,0.f};
    if (row < 10000){
      const unsigned short* p = P + (long long)row*ldp + colOff + cb + c4;
      for (int s2 = 0; s2 < S; ++s2){
        us4 tt = *(const us4*)(p + (long long)s2*stride);
        sv[0] += bf2f(tt.x); sv[1] += bf2f(tt.y);
        sv[2] += bf2f(tt.z); sv[3] += bf2f(tt.w);
      }
      us4 h = *(const us4*)(H + (long long)row*256 + cb + c4);
      sv[0] = 0.5f*sv[0] + 0.5f*bf2f(h.x);
      sv[1] = 0.5f*sv[1] + 0.5f*bf2f(h.y);
      sv[2] = 0.5f*sv[2] + 0.5f*bf2f(h.z);
      sv[3] = 0.5f*sv[3] + 0.5f*bf2f(h.w);
    }
    t[c4+0][r] = f2bf(sv[0]); t[c4+1][r] = f2bf(sv[1]);
    t[c4+2][r] = f2bf(sv[2]); t[c4+3][r] = f2bf(sv[3]);
  }
  __syncthreads();
  #pragma unroll
  for (int it = 0; it < 4; ++it){
    int idx = it*256 + threadIdx.x;
    int ro = idx >> 4, co4 = (idx & 15)*4;
    us4 v; v.x=t[ro][co4]; v.y=t[ro][co4+1]; v.z=t[ro][co4+2]; v.w=t[ro][co4+3];
    *(us4*)(outT + (long long)(cb+ro)*LDA + rb + co4) = v;
  }
}

// ---- reduce partials + sigmoid -> f32 res [10000][128] ----
__global__ void k_reduce_sig(const unsigned short* __restrict__ P, int S,
                             float* __restrict__ out)
{
  const long long stride = MROWS * 128LL;
  const int idx = blockIdx.x*256 + threadIdx.x;
  const int row = idx >> 5;
  const int c4 = (idx & 31)*4;
  const unsigned short* p = P + (long long)row*128 + c4;
  float sv[4] = {0.f,0.f,0.f,0.f};
  for (int s2 = 0; s2 < S; ++s2){
    us4 tt = *(const us4*)(p + (long long)s2*stride);
    sv[0] += bf2f(tt.x); sv[1] += bf2f(tt.y);
    sv[2] += bf2f(tt.z); sv[3] += bf2f(tt.w);
  }
  float4 o;
  o.x = 1.0f/(1.0f + expf(-sv[0]));
  o.y = 1.0f/(1.0f + expf(-sv[1]));
  o.z = 1.0f/(1.0f + expf(-sv[2]));
  o.w = 1.0f/(1.0f + expf(-sv[3]));
  *(float4*)(out + (long long)row*128 + c4) = o;
}

// ---- final reduce: Z3 = 0.5*sum + 0.5*zn -> f32 out ----
__global__ void k_reduce2(const unsigned short* __restrict__ P, int S, int ldp,
                          float* __restrict__ out, const unsigned short* __restrict__ H)
{
  const long long stride = MROWS * (long long)ldp;
  const int idx = blockIdx.x*256 + threadIdx.x;
  const int row = idx >> 6;
  const int c4 = (idx & 63)*4;
  const unsigned short* p = P + (long long)row*ldp + c4;
  float sv[4] = {0.f,0.f,0.f,0.f};
  for (int s2 = 0; s2 < S; ++s2){
    us4 tt = *(const us4*)(p + (long long)s2*stride);
    sv[0] += bf2f(tt.x); sv[1] += bf2f(tt.y);
    sv[2] += bf2f(tt.z); sv[3] += bf2f(tt.w);
  }
  us4 h = *(const us4*)(H + (long long)row*256 + c4);
  float4 o;
  o.x = 0.5f*sv[0] + 0.5f*bf2f(h.x);
  o.y = 0.5f*sv[1] + 0.5f*bf2f(h.y);
  o.z = 0.5f*sv[2] + 0.5f*bf2f(h.z);
  o.w = 0.5f*sv[3] + 0.5f*bf2f(h.w);
  *(float4*)(out + (long long)row*256 + c4) = o;
}

extern "C" void kernel_launch(void* const* d_in, const int* in_sizes, int n_in,
                              void* d_out, int out_size, void* d_ws, size_t ws_size,
                              hipStream_t stream)
{
  const float* g   = (const float*)d_in[0];
  const float* z   = (const float*)d_in[1];
  const float* W1  = (const float*)d_in[2];
  const float* W1_ = (const float*)d_in[3];
  const float* W2  = (const float*)d_in[4];

  char* ws = (char*)d_ws;
  size_t off = 0;
  auto alloc = [&](size_t bytes)->void*{
    void* p = ws + off; off += (bytes + 255) & ~(size_t)255; return p;
  };
  unsigned short* g16  = (unsigned short*)alloc(40ULL*157*GTILE*2);  // tiled, 206 MB
  unsigned short* zT   = (unsigned short*)alloc(128ULL*10048*2);
  unsigned short* W1c  = (unsigned short*)alloc(256ULL*128*2);
  unsigned short* W1_c = (unsigned short*)alloc(256ULL*256*2);
  unsigned short* W2c  = (unsigned short*)alloc(128ULL*256*2);
  unsigned short* Tbuf = (unsigned short*)alloc(512ULL*10048*2);
  unsigned short* zn   = (unsigned short*)alloc(10000ULL*256*2);
  unsigned short* Xbuf = (unsigned short*)alloc(10000ULL*256*2);
  unsigned short* P    = (unsigned short*)alloc(10240ULL*1536*2);
  (void)ws_size; (void)in_sizes; (void)n_in; (void)out_size;

  float* res  = (float*)d_out;
  float* Zout = (float*)d_out + 10000LL*128;
  unsigned short* y2T = Tbuf + 256LL*LDA;

  k_zero<<<dim3(12), dim3(256), 0, stream>>>(Tbuf);
  k_tconv_z<<<dim3(157,2), dim3(256), 0, stream>>>(z, zT);
  k_conv_w<<<dim3(120), dim3(256), 0, stream>>>(W1, W1c, 256*128/4,
                                                W1_, W1_c, 256*256/4,
                                                W2, W2c, 128*256/4);

  // t0 = g @ z (writes tiled g16 + partials), S=6, XCD-remapped 240 blocks
  k_gemm_t0<<<dim3(240), dim3(512), 0, stream>>>(g, zT, g16, P, 6);
  // z1^T -> Tbuf rows 0..255
  k_small<256,128,128,6,0><<<dim3(125), dim3(320), 0, stream>>>(P, W1c, Tbuf, nullptr, nullptr, 1);
  // t1 = g @ z1
  k_gemm8<256><<<dim3(240), dim3(512), 0, stream>>>(g16, Tbuf, P, 6, 256);
  // znT -> Tbuf rows 0..255, zn row, z_ row -> Xbuf
  k_small<256,256,256,6,1><<<dim3(125), dim3(320), 0, stream>>>(P, W1_c, Tbuf, zn, Xbuf, 0);
  // y2^T = T(z_ @ W2^T) -> Tbuf rows 256..383
  k_small<128,256,256,1,0><<<dim3(125), dim3(320), 0, stream>>>(Xbuf, W2c, y2T, nullptr, nullptr, 0);
  // u1 = g @ zn
  k_gemm8<256><<<dim3(240), dim3(512), 0, stream>>>(g16, Tbuf, P, 6, 256);
  // Z1^T -> Tbuf rows 0..255
  k_reduce_T<<<dim3(157,4), dim3(256), 0, stream>>>(P, 6, 256, 0, Tbuf, zn);
  // r = g @ y2 (N=128)
  k_gemm8<128><<<dim3(240), dim3(512), 0, stream>>>(g16, y2T, P, 6, 128);
  // res = sigmoid(r)
  k_reduce_sig<<<dim3(1250), dim3(256), 0, stream>>>(P, 6, res);
  // Z2
  k_gemm8<256><<<dim3(240), dim3(512), 0, stream>>>(g16, Tbuf, P, 6, 256);
  k_reduce_T<<<dim3(157,4), dim3(256), 0, stream>>>(P, 6, 256, 0, Tbuf, zn);
  // Z3 -> f32 d_out
  k_gemm8<256><<<dim3(240), dim3(512), 0, stream>>>(g16, Tbuf, P, 6, 256);
  k_reduce2<<<dim3(2500), dim3(256), 0, stream>>>(P, 6, 256, Zout, zn);
}